// Round 1
// baseline (475.794 us; speedup 1.0000x reference)
//
#include <hip/hip_runtime.h>
#include <hip/hip_bf16.h>

// ---------------------------------------------------------------------------
// Transformer block forward (B=4, T=2048, C=1024, F=4096), all-GEMMs in bf16
// MFMA (16x16x32), fp32 accumulate, fused epilogues.
// ---------------------------------------------------------------------------

typedef __bf16 bf16x8_t __attribute__((ext_vector_type(8)));
typedef float f32x4_t __attribute__((ext_vector_type(4)));

__device__ __forceinline__ unsigned short f2bf(float f) {
    unsigned int u = __float_as_uint(f);
    u += 0x7fffu + ((u >> 16) & 1u);   // round-to-nearest-even
    return (unsigned short)(u >> 16);
}

// LDS address swizzle: row stride 128 B (64 bf16), XOR 16B-unit by
// f(r) = (r ^ (r>>3)) & 7. Keeps 16B alignment; balances banks for:
//  - b128 linear stage writes (conflict-free)
//  - b128 fragment reads (2-way, free)
//  - u16 transpose scatter writes (4-way)
__device__ __forceinline__ int swz(int r, int cbyte) {
    return (r << 7) + (cbyte ^ ((((r >> 3) ^ r) & 7) << 4));
}

enum { EPI_F32 = 0, EPI_BF16 = 1, EPI_BIAS_RELU_BF16 = 2, EPI_RESID_F32 = 3,
       EPI_BIAS_RESID_F32 = 4 };

// C = A @ B (+epilogue).  A: [M][K] bf16 row-major.
// BT=true:  B given as [N][K] (row-major) — i.e. C = A @ B^T of that array.
// BT=false: B given as [K][N] (row-major), transposed into LDS on stage.
// CSKIP: skip tiles entirely above the causal diagonal (scores GEMM).
// KLIM:  limit K-loop to row0+BM (PV GEMM with causal-zeroed A).
template <int EPI, bool BT, bool CSKIP, bool KLIM>
__global__ __launch_bounds__(256, 2) void gemm_k(
    const unsigned short* __restrict__ A,
    const unsigned short* __restrict__ B,
    void* __restrict__ Cout,
    const float* __restrict__ bias,
    const float* __restrict__ resid,
    int M, int N, int K, float scale,
    long long batA, long long batB, long long batC, long long batR)
{
    constexpr int BM = 128, BN = 128, BK = 32;
    __shared__ __align__(16) unsigned char sA[BM * 128];
    __shared__ __align__(16) unsigned char sB[BN * 128];

    const int row0 = blockIdx.y * BM;
    const int col0 = blockIdx.x * BN;
    if (CSKIP && col0 > row0) return;           // fully-masked tile

    const int bz = blockIdx.z;
    A += (long long)bz * batA;
    B += (long long)bz * batB;

    const int tid  = threadIdx.x;
    const int lane = tid & 63;
    const int wid  = tid >> 6;
    const int wr   = (wid >> 1) * 64;   // wave sub-tile origin (rows)
    const int wc   = (wid & 1) * 64;    // wave sub-tile origin (cols)
    const int lr   = lane & 15;
    const int lg   = lane >> 4;

    int Keff = K;
    if (KLIM) { int kl = row0 + BM; Keff = kl < K ? kl : K; }
    const int nkt = Keff / BK;

    const int lda = K;
    const int ldb = BT ? K : N;
    const int ldc = N;

    // ---- precomputed LDS offsets (loop-invariant) ----
    int aoff[4], boff[4];
#pragma unroll
    for (int m = 0; m < 4; ++m) aoff[m] = swz(wr + m * 16 + lr, lg * 16);
#pragma unroll
    for (int n = 0; n < 4; ++n) boff[n] = swz(wc + n * 16 + lr, lg * 16);

    const int cA0 = tid, cA1 = tid + 256;            // A-stage chunks
    const int sAo0 = swz(cA0 >> 2, (cA0 & 3) << 4);
    const int sAo1 = swz(cA1 >> 2, (cA1 & 3) << 4);

    int4 a0, a1, b0, b1;

    auto loadA = [&](int kt) {
        const unsigned short* Ap = A + (long long)row0 * lda + kt * BK;
        a0 = *(const int4*)(Ap + (long long)(cA0 >> 2) * lda + (cA0 & 3) * 8);
        a1 = *(const int4*)(Ap + (long long)(cA1 >> 2) * lda + (cA1 & 3) * 8);
    };
    auto loadB = [&](int kt) {
        if (BT) {
            const unsigned short* Bp = B + (long long)col0 * ldb + kt * BK;
            b0 = *(const int4*)(Bp + (long long)(cA0 >> 2) * ldb + (cA0 & 3) * 8);
            b1 = *(const int4*)(Bp + (long long)(cA1 >> 2) * ldb + (cA1 & 3) * 8);
        } else {
            const unsigned short* Bp = B + (long long)(kt * BK) * ldb + col0;
            b0 = *(const int4*)(Bp + (long long)(cA0 >> 4) * ldb + (cA0 & 15) * 8);
            b1 = *(const int4*)(Bp + (long long)(cA1 >> 4) * ldb + (cA1 & 15) * 8);
        }
    };
    auto storeAB = [&]() {
        *(int4*)(sA + sAo0) = a0;
        *(int4*)(sA + sAo1) = a1;
        if (BT) {
            *(int4*)(sB + sAo0) = b0;
            *(int4*)(sB + sAo1) = b1;
        } else {
            bf16x8_t v0 = __builtin_bit_cast(bf16x8_t, b0);
            bf16x8_t v1 = __builtin_bit_cast(bf16x8_t, b1);
            const int k0 = cA0 >> 4, nb0 = cA0 & 15;
            const int k1 = cA1 >> 4, nb1 = cA1 & 15;
#pragma unroll
            for (int j = 0; j < 8; ++j) {
                *(__bf16*)(sB + swz(nb0 * 8 + j, k0 * 2)) = v0[j];
                *(__bf16*)(sB + swz(nb1 * 8 + j, k1 * 2)) = v1[j];
            }
        }
    };

    f32x4_t acc[4][4];
#pragma unroll
    for (int m = 0; m < 4; ++m)
#pragma unroll
        for (int n = 0; n < 4; ++n)
            acc[m][n] = (f32x4_t){0.f, 0.f, 0.f, 0.f};

    loadA(0); loadB(0);
    for (int kt = 0; kt < nkt; ++kt) {
        __syncthreads();            // previous tile's reads complete
        storeAB();
        __syncthreads();            // tile visible
        if (kt + 1 < nkt) { loadA(kt + 1); loadB(kt + 1); }   // prefetch

        bf16x8_t af[4], bfv[4];
#pragma unroll
        for (int m = 0; m < 4; ++m) af[m]  = *(const bf16x8_t*)(sA + aoff[m]);
#pragma unroll
        for (int n = 0; n < 4; ++n) bfv[n] = *(const bf16x8_t*)(sB + boff[n]);
#pragma unroll
        for (int m = 0; m < 4; ++m)
#pragma unroll
            for (int n = 0; n < 4; ++n)
                acc[m][n] = __builtin_amdgcn_mfma_f32_16x16x32_bf16(
                    af[m], bfv[n], acc[m][n], 0, 0, 0);
    }

    // ---- epilogue ----
    float* Cf = (float*)Cout + (long long)bz * batC;
    unsigned short* Cb = (unsigned short*)Cout + (long long)bz * batC;
    const float* R = nullptr;
    if constexpr (EPI == EPI_RESID_F32 || EPI == EPI_BIAS_RESID_F32)
        R = resid + (long long)bz * batR;

#pragma unroll
    for (int m = 0; m < 4; ++m)
#pragma unroll
        for (int n = 0; n < 4; ++n)
#pragma unroll
            for (int j = 0; j < 4; ++j) {
                const int row = row0 + wr + m * 16 + lg * 4 + j;
                const int col = col0 + wc + n * 16 + lr;
                const long long idx = (long long)row * ldc + col;
                float v = acc[m][n][j] * scale;
                if constexpr (EPI == EPI_F32) {
                    Cf[idx] = v;
                } else if constexpr (EPI == EPI_BF16) {
                    Cb[idx] = f2bf(v);
                } else if constexpr (EPI == EPI_BIAS_RELU_BF16) {
                    v += bias[col];
                    v = v > 0.f ? v : 0.f;
                    Cb[idx] = f2bf(v);
                } else if constexpr (EPI == EPI_RESID_F32) {
                    Cf[idx] = v + R[idx];
                } else {  // EPI_BIAS_RESID_F32
                    Cf[idx] = v + bias[col] + R[idx];
                }
            }
}

// ---------------- LayerNorm: one 256-thread block per 1024-elem row --------
__global__ __launch_bounds__(256) void ln_k(
    const float* __restrict__ x, const float* __restrict__ g,
    const float* __restrict__ be, unsigned short* __restrict__ out)
{
    __shared__ float sred[8];
    const long long row = blockIdx.x;
    const int tid = threadIdx.x;
    float4 v = ((const float4*)(x + row * 1024))[tid];
    float s = v.x + v.y + v.z + v.w;
    float q = v.x * v.x + v.y * v.y + v.z * v.z + v.w * v.w;
#pragma unroll
    for (int off = 32; off > 0; off >>= 1) {
        s += __shfl_xor(s, off);
        q += __shfl_xor(q, off);
    }
    if ((tid & 63) == 0) { sred[tid >> 6] = s; sred[4 + (tid >> 6)] = q; }
    __syncthreads();
    s = sred[0] + sred[1] + sred[2] + sred[3];
    q = sred[4] + sred[5] + sred[6] + sred[7];
    const float mean = s * (1.0f / 1024.0f);
    const float var  = q * (1.0f / 1024.0f) - mean * mean;
    const float rstd = rsqrtf(var + 1e-5f);
    float4 gv = ((const float4*)g)[tid];
    float4 bv = ((const float4*)be)[tid];
    ushort4 o;
    o.x = f2bf((v.x - mean) * rstd * gv.x + bv.x);
    o.y = f2bf((v.y - mean) * rstd * gv.y + bv.y);
    o.z = f2bf((v.z - mean) * rstd * gv.z + bv.z);
    o.w = f2bf((v.w - mean) * rstd * gv.w + bv.w);
    *(ushort4*)(out + row * 1024 + tid * 4) = o;
}

// ------------- causal row softmax: S fp32 -> P bf16 (zero-padded) ----------
__global__ __launch_bounds__(256) void softmax_k(
    const float* __restrict__ S, unsigned short* __restrict__ P, int T)
{
    __shared__ float sred[4];
    const int t = blockIdx.x;
    const long long base = ((long long)blockIdx.y * T + t) * (long long)T;
    const float* srow = S + base;
    unsigned short* prow = P + base;
    const int n = t + 1;                       // valid causal length
    const int lim = ((t >> 7) + 1) << 7;       // zero-fill to tile boundary
    const int tid = threadIdx.x;

    float mx = -3.0e38f;
    for (int i = tid; i < n; i += 256) mx = fmaxf(mx, srow[i]);
#pragma unroll
    for (int off = 32; off > 0; off >>= 1) mx = fmaxf(mx, __shfl_xor(mx, off));
    if ((tid & 63) == 0) sred[tid >> 6] = mx;
    __syncthreads();
    mx = fmaxf(fmaxf(sred[0], sred[1]), fmaxf(sred[2], sred[3]));

    float sum = 0.f;
    for (int i = tid; i < n; i += 256) sum += __expf(srow[i] - mx);
#pragma unroll
    for (int off = 32; off > 0; off >>= 1) sum += __shfl_xor(sum, off);
    __syncthreads();                            // sred reuse
    if ((tid & 63) == 0) sred[tid >> 6] = sum;
    __syncthreads();
    sum = sred[0] + sred[1] + sred[2] + sred[3];
    const float inv = 1.0f / sum;

    for (int i = tid; i < n; i += 256) prow[i] = f2bf(__expf(srow[i] - mx) * inv);
    for (int i = n + tid; i < lim; i += 256) prow[i] = 0;
}

// ---------------------- fp32 -> bf16 convert (vectorized) ------------------
__global__ __launch_bounds__(256) void f2b_k(
    const float4* __restrict__ in, ushort4* __restrict__ out, int n4)
{
    int i = blockIdx.x * 256 + threadIdx.x;
    const int stride = gridDim.x * 256;
    for (; i < n4; i += stride) {
        float4 v = in[i];
        ushort4 o;
        o.x = f2bf(v.x); o.y = f2bf(v.y); o.z = f2bf(v.z); o.w = f2bf(v.w);
        out[i] = o;
    }
}

// ---------------------------------------------------------------------------
extern "C" void kernel_launch(void* const* d_in, const int* in_sizes, int n_in,
                              void* d_out, int out_size, void* d_ws, size_t ws_size,
                              hipStream_t stream)
{
    const int B = 4, T = 2048, C = 1024, F = 4096;
    const float* x   = (const float*)d_in[0];
    const float* Wk  = (const float*)d_in[1];
    const float* Wq  = (const float*)d_in[2];
    const float* Wv  = (const float*)d_in[3];
    const float* W1  = (const float*)d_in[4];
    const float* b1  = (const float*)d_in[5];
    const float* W2  = (const float*)d_in[6];
    const float* b2  = (const float*)d_in[7];
    const float* g1  = (const float*)d_in[8];
    const float* be1 = (const float*)d_in[9];
    const float* g2  = (const float*)d_in[10];
    const float* be2 = (const float*)d_in[11];

    char* ws = (char*)d_ws;
    const size_t MB = 1ull << 20;
    unsigned short* h    = (unsigned short*)(ws + 0);         // 16 MiB (reused for h2)
    unsigned short* q    = (unsigned short*)(ws + 16 * MB);   // 16 MiB
    unsigned short* k    = (unsigned short*)(ws + 32 * MB);   // 16 MiB
    unsigned short* v    = (unsigned short*)(ws + 48 * MB);   // 16 MiB
    float*          xres = (float*)(ws + 64 * MB);            // 32 MiB
    float*          S    = (float*)(ws + 96 * MB);            // 64 MiB
    unsigned short* ff1  = (unsigned short*)(ws + 96 * MB);   // 64 MiB (aliases S; S dead by then)
    unsigned short* P    = (unsigned short*)(ws + 160 * MB);  // 32 MiB
    unsigned short* wq   = (unsigned short*)(ws + 192 * MB);  // 2 MiB
    unsigned short* wk   = (unsigned short*)(ws + 194 * MB);  // 2 MiB
    unsigned short* wv   = (unsigned short*)(ws + 196 * MB);  // 2 MiB
    unsigned short* w1   = (unsigned short*)(ws + 198 * MB);  // 8 MiB
    unsigned short* w2   = (unsigned short*)(ws + 206 * MB);  // 8 MiB  (end: 214 MiB)

    // weight dtype converts
    f2b_k<<<dim3(512),  256, 0, stream>>>((const float4*)Wq, (ushort4*)wq, C * C / 4);
    f2b_k<<<dim3(512),  256, 0, stream>>>((const float4*)Wk, (ushort4*)wk, C * C / 4);
    f2b_k<<<dim3(512),  256, 0, stream>>>((const float4*)Wv, (ushort4*)wv, C * C / 4);
    f2b_k<<<dim3(2048), 256, 0, stream>>>((const float4*)W1, (ushort4*)w1, C * F / 4);
    f2b_k<<<dim3(2048), 256, 0, stream>>>((const float4*)W2, (ushort4*)w2, F * C / 4);

    // LN1: h = LN(x, g1, be1)
    ln_k<<<dim3(B * T), 256, 0, stream>>>(x, g1, be1, h);

    // q/k/v = h @ W{q,k,v}   (M=8192, N=1024, K=1024)
    dim3 gqkv(C / 128, (B * T) / 128, 1);
    gemm_k<EPI_BF16, false, false, false><<<gqkv, 256, 0, stream>>>(
        h, wq, q, nullptr, nullptr, B * T, C, C, 1.0f, 0, 0, 0, 0);
    gemm_k<EPI_BF16, false, false, false><<<gqkv, 256, 0, stream>>>(
        h, wk, k, nullptr, nullptr, B * T, C, C, 1.0f, 0, 0, 0, 0);
    gemm_k<EPI_BF16, false, false, false><<<gqkv, 256, 0, stream>>>(
        h, wv, v, nullptr, nullptr, B * T, C, C, 1.0f, 0, 0, 0, 0);

    // S = q @ k^T / 32  (per batch; causal tiles only)
    dim3 gsc(T / 128, T / 128, B);
    gemm_k<EPI_F32, true, true, false><<<gsc, 256, 0, stream>>>(
        q, k, S, nullptr, nullptr, T, T, C, 0.03125f,
        (long long)T * C, (long long)T * C, (long long)T * T, 0);

    // P = causal softmax(S), bf16, zero-padded to tile boundary
    softmax_k<<<dim3(T, B), 256, 0, stream>>>(S, P, T);

    // xres = x + P @ v   (K limited to causal extent)
    dim3 gsa(C / 128, T / 128, B);
    gemm_k<EPI_RESID_F32, false, false, true><<<gsa, 256, 0, stream>>>(
        P, v, xres, nullptr, x, T, C, T, 1.0f,
        (long long)T * T, (long long)T * C, (long long)T * C, (long long)T * C);

    // LN2: h = LN(xres, g2, be2)
    ln_k<<<dim3(B * T), 256, 0, stream>>>(xres, g2, be2, h);

    // ff1 = relu(h @ W1 + b1)   (M=8192, N=4096, K=1024)
    dim3 gf1(F / 128, (B * T) / 128, 1);
    gemm_k<EPI_BIAS_RELU_BF16, false, false, false><<<gf1, 256, 0, stream>>>(
        h, w1, ff1, b1, nullptr, B * T, F, C, 1.0f, 0, 0, 0, 0);

    // out = xres + ff1 @ W2 + b2   (M=8192, N=1024, K=4096)
    dim3 gf2(C / 128, (B * T) / 128, 1);
    gemm_k<EPI_BIAS_RESID_F32, false, false, false><<<gf2, 256, 0, stream>>>(
        ff1, w2, (float*)d_out, b2, xres, B * T, C, F, 1.0f, 0, 0, 0, 0);
}

// Round 2
// 419.149 us; speedup vs baseline: 1.1351x; 1.1351x over previous
//
#include <hip/hip_runtime.h>
#include <hip/hip_bf16.h>

// ---------------------------------------------------------------------------
// Transformer block forward (B=4, T=2048, C=1024, F=4096).
// All GEMMs: bf16 MFMA 16x16x32, fp32 accum, m97 structure:
// global_load_lds width-16 staging into linear LDS, 2-barrier K-loop.
// All B operands in [N][K] (BT) layout: weights pre-transposed by tconv_k,
// v produced directly transposed via vT = Wv^T @ h^T.
// ---------------------------------------------------------------------------

typedef __bf16 bf16x8_t __attribute__((ext_vector_type(8)));
typedef float f32x4_t __attribute__((ext_vector_type(4)));

__device__ __forceinline__ unsigned short f2bf(float f) {
    unsigned int u = __float_as_uint(f);
    u += 0x7fffu + ((u >> 16) & 1u);   // round-to-nearest-even
    return (unsigned short)(u >> 16);
}

__device__ __forceinline__ void gload16(const void* g, void* lds) {
    __builtin_amdgcn_global_load_lds(
        (const __attribute__((address_space(1))) unsigned int*)g,
        (__attribute__((address_space(3))) unsigned int*)lds, 16, 0, 0);
}

enum { EPI_F32 = 0, EPI_BF16 = 1, EPI_BIAS_RELU_BF16 = 2, EPI_RESID_F32 = 3,
       EPI_BIAS_RESID_F32 = 4 };

// C = A @ B^T (+epilogue).  A: [M][lda] bf16 row-major, B: [N][ldb] bf16.
// CSKIP: skip tiles above the causal diagonal (scores GEMM).
// KLIM:  limit K-loop to row0+BM (PV GEMM; A rows are causal-zero beyond).
template <int EPI, bool CSKIP, bool KLIM>
__global__ __launch_bounds__(256, 3) void gemm_k(
    const unsigned short* __restrict__ A,
    const unsigned short* __restrict__ B,
    void* __restrict__ Cout,
    const float* __restrict__ bias,
    const float* __restrict__ resid,
    int M, int N, int K, int lda, int ldb, float scale,
    long long batA, long long batB, long long batC, long long batR)
{
    constexpr int BM = 128, BN = 128, BK = 32;
    __shared__ __align__(16) unsigned short sA[BM * BK];   // 8 KiB, linear
    __shared__ __align__(16) unsigned short sB[BN * BK];   // 8 KiB, linear

    const int row0 = blockIdx.y * BM;
    const int col0 = blockIdx.x * BN;
    if (CSKIP && col0 > row0) return;           // fully-masked tile

    const int bz = blockIdx.z;
    const unsigned short* Ab = A + (long long)bz * batA + (long long)row0 * lda;
    const unsigned short* Bb = B + (long long)bz * batB + (long long)col0 * ldb;

    const int tid  = threadIdx.x;
    const int lane = tid & 63;
    const int wid  = tid >> 6;
    const int wr   = (wid >> 1) * 64;   // wave sub-tile origin (rows)
    const int wc   = (wid & 1) * 64;    // wave sub-tile origin (cols)
    const int lr   = lane & 15;
    const int lg   = lane >> 4;

    int Keff = K;
    if (KLIM) { int kl = row0 + BM; Keff = kl < K ? kl : K; }
    const int nkt = Keff / BK;

    // ---- staging: 512 16B-chunks per 128x32 tile; chunk c -> row c>>2,
    // in-row 16B-slot c&3.  Wave w stages chunks [64w,64w+64) and +256.
    // LDS dest is wave-uniform base; HW scatters lane l at +16*l.
    const int c0 = wid * 64 + lane;
    const int c1 = c0 + 256;
    const unsigned short* ga0 = Ab + (long long)(c0 >> 2) * lda + (c0 & 3) * 8;
    const unsigned short* ga1 = Ab + (long long)(c1 >> 2) * lda + (c1 & 3) * 8;
    const unsigned short* gb0 = Bb + (long long)(c0 >> 2) * ldb + (c0 & 3) * 8;
    const unsigned short* gb1 = Bb + (long long)(c1 >> 2) * ldb + (c1 & 3) * 8;
    unsigned short* sAd0 = sA + (wid * 64) * 8;
    unsigned short* sAd1 = sA + (256 + wid * 64) * 8;
    unsigned short* sBd0 = sB + (wid * 64) * 8;
    unsigned short* sBd1 = sB + (256 + wid * 64) * 8;

    // fragment read offsets (elements): row*(BK) + lg*8
    int aoff[4], boff[4];
#pragma unroll
    for (int m = 0; m < 4; ++m) aoff[m] = (wr + m * 16 + lr) * BK + lg * 8;
#pragma unroll
    for (int n = 0; n < 4; ++n) boff[n] = (wc + n * 16 + lr) * BK + lg * 8;

    f32x4_t acc[4][4];
#pragma unroll
    for (int m = 0; m < 4; ++m)
#pragma unroll
        for (int n = 0; n < 4; ++n)
            acc[m][n] = (f32x4_t){0.f, 0.f, 0.f, 0.f};

    for (int kt = 0; kt < nkt; ++kt) {
        __syncthreads();                 // prev tile's ds_reads complete
        const int ke = kt * BK;
        gload16(ga0 + ke, sAd0);
        gload16(ga1 + ke, sAd1);
        gload16(gb0 + ke, sBd0);
        gload16(gb1 + ke, sBd1);
        __syncthreads();                 // compiler drains vmcnt(0) before barrier

        bf16x8_t af[4], bfv[4];
#pragma unroll
        for (int m = 0; m < 4; ++m) af[m]  = *(const bf16x8_t*)(sA + aoff[m]);
#pragma unroll
        for (int n = 0; n < 4; ++n) bfv[n] = *(const bf16x8_t*)(sB + boff[n]);
#pragma unroll
        for (int m = 0; m < 4; ++m)
#pragma unroll
            for (int n = 0; n < 4; ++n)
                acc[m][n] = __builtin_amdgcn_mfma_f32_16x16x32_bf16(
                    af[m], bfv[n], acc[m][n], 0, 0, 0);
    }

    // ---- epilogue ----
    const int ldc = N;
    float* Cf = (float*)Cout + (long long)bz * batC;
    unsigned short* Cb = (unsigned short*)Cout + (long long)bz * batC;
    const float* R = nullptr;
    if constexpr (EPI == EPI_RESID_F32 || EPI == EPI_BIAS_RESID_F32)
        R = resid + (long long)bz * batR;

#pragma unroll
    for (int m = 0; m < 4; ++m)
#pragma unroll
        for (int n = 0; n < 4; ++n)
#pragma unroll
            for (int j = 0; j < 4; ++j) {
                const int row = row0 + wr + m * 16 + lg * 4 + j;
                const int col = col0 + wc + n * 16 + lr;
                const long long idx = (long long)row * ldc + col;
                float v = acc[m][n][j] * scale;
                if constexpr (EPI == EPI_F32) {
                    Cf[idx] = v;
                } else if constexpr (EPI == EPI_BF16) {
                    Cb[idx] = f2bf(v);
                } else if constexpr (EPI == EPI_BIAS_RELU_BF16) {
                    v += bias[col];
                    v = v > 0.f ? v : 0.f;
                    Cb[idx] = f2bf(v);
                } else if constexpr (EPI == EPI_RESID_F32) {
                    Cf[idx] = v + R[idx];
                } else {  // EPI_BIAS_RESID_F32
                    Cf[idx] = v + bias[col] + R[idx];
                }
            }
}

// ------------- transpose + fp32->bf16 convert: in [R][Cc] -> out [Cc][R] ----
__global__ __launch_bounds__(256) void tconv_k(
    const float* __restrict__ in, unsigned short* __restrict__ out,
    int R, int Cc)
{
    __shared__ float t[64][65];
    const int r0 = blockIdx.y * 64, c0 = blockIdx.x * 64;
    const int tid = threadIdx.x;
    const int a = tid >> 4;     // 0..15
    const int b = tid & 15;     // 0..15
#pragma unroll
    for (int i = 0; i < 4; ++i) {
        const int row = a + i * 16;
        float4 v = *(const float4*)(in + (long long)(r0 + row) * Cc + c0 + b * 4);
        t[row][b * 4 + 0] = v.x; t[row][b * 4 + 1] = v.y;
        t[row][b * 4 + 2] = v.z; t[row][b * 4 + 3] = v.w;
    }
    __syncthreads();
#pragma unroll
    for (int i = 0; i < 4; ++i) {
        const int oc = a + i * 16;
        ushort4 o;
        o.x = f2bf(t[b * 4 + 0][oc]);
        o.y = f2bf(t[b * 4 + 1][oc]);
        o.z = f2bf(t[b * 4 + 2][oc]);
        o.w = f2bf(t[b * 4 + 3][oc]);
        *(ushort4*)(out + (long long)(c0 + oc) * R + r0 + b * 4) = o;
    }
}

// ---------------- LayerNorm: one 256-thread block per 1024-elem row --------
__global__ __launch_bounds__(256) void ln_k(
    const float* __restrict__ x, const float* __restrict__ g,
    const float* __restrict__ be, unsigned short* __restrict__ out)
{
    __shared__ float sred[8];
    const long long row = blockIdx.x;
    const int tid = threadIdx.x;
    float4 v = ((const float4*)(x + row * 1024))[tid];
    float s = v.x + v.y + v.z + v.w;
    float q = v.x * v.x + v.y * v.y + v.z * v.z + v.w * v.w;
#pragma unroll
    for (int off = 32; off > 0; off >>= 1) {
        s += __shfl_xor(s, off);
        q += __shfl_xor(q, off);
    }
    if ((tid & 63) == 0) { sred[tid >> 6] = s; sred[4 + (tid >> 6)] = q; }
    __syncthreads();
    s = sred[0] + sred[1] + sred[2] + sred[3];
    q = sred[4] + sred[5] + sred[6] + sred[7];
    const float mean = s * (1.0f / 1024.0f);
    const float var  = q * (1.0f / 1024.0f) - mean * mean;
    const float rstd = rsqrtf(var + 1e-5f);
    float4 gv = ((const float4*)g)[tid];
    float4 bv = ((const float4*)be)[tid];
    ushort4 o;
    o.x = f2bf((v.x - mean) * rstd * gv.x + bv.x);
    o.y = f2bf((v.y - mean) * rstd * gv.y + bv.y);
    o.z = f2bf((v.z - mean) * rstd * gv.z + bv.z);
    o.w = f2bf((v.w - mean) * rstd * gv.w + bv.w);
    *(ushort4*)(out + row * 1024 + tid * 4) = o;
}

// ------------- causal row softmax: S fp32 -> P bf16 (zero-padded) ----------
// Row staged in LDS: one global read of S, exp stored and reused.
__global__ __launch_bounds__(256) void softmax_k(
    const float* __restrict__ S, unsigned short* __restrict__ P, int T)
{
    __shared__ float rowl[2048];
    __shared__ float sred[4];
    const int t = blockIdx.x;
    const long long base = ((long long)blockIdx.y * T + t) * (long long)T;
    const float* srow = S + base;
    unsigned short* prow = P + base;
    const int n = t + 1;                       // valid causal length
    const int lim = ((t >> 7) + 1) << 7;       // zero-fill to tile boundary
    const int tid = threadIdx.x;

    const int nv = n >> 2;
    for (int i = tid; i < nv; i += 256)
        ((float4*)rowl)[i] = ((const float4*)srow)[i];
    for (int i = (nv << 2) + tid; i < n; i += 256) rowl[i] = srow[i];
    __syncthreads();

    float mx = -3.0e38f;
    for (int i = tid; i < n; i += 256) mx = fmaxf(mx, rowl[i]);
#pragma unroll
    for (int off = 32; off > 0; off >>= 1) mx = fmaxf(mx, __shfl_xor(mx, off));
    if ((tid & 63) == 0) sred[tid >> 6] = mx;
    __syncthreads();
    mx = fmaxf(fmaxf(sred[0], sred[1]), fmaxf(sred[2], sred[3]));
    __syncthreads();                            // sred reuse

    float sum = 0.f;
    for (int i = tid; i < n; i += 256) {
        float e = __expf(rowl[i] - mx);
        rowl[i] = e;                            // own slots only — no race
        sum += e;
    }
#pragma unroll
    for (int off = 32; off > 0; off >>= 1) sum += __shfl_xor(sum, off);
    if ((tid & 63) == 0) sred[tid >> 6] = sum;
    __syncthreads();
    sum = sred[0] + sred[1] + sred[2] + sred[3];
    const float inv = 1.0f / sum;

    for (int i = tid; i < n; i += 256) prow[i] = f2bf(rowl[i] * inv);
    for (int i = n + tid; i < lim; i += 256) prow[i] = 0;
}

// ---------------------------------------------------------------------------
extern "C" void kernel_launch(void* const* d_in, const int* in_sizes, int n_in,
                              void* d_out, int out_size, void* d_ws, size_t ws_size,
                              hipStream_t stream)
{
    const int B = 4, T = 2048, C = 1024, F = 4096;
    const float* x   = (const float*)d_in[0];
    const float* Wk  = (const float*)d_in[1];
    const float* Wq  = (const float*)d_in[2];
    const float* Wv  = (const float*)d_in[3];
    const float* W1  = (const float*)d_in[4];
    const float* b1  = (const float*)d_in[5];
    const float* W2  = (const float*)d_in[6];
    const float* b2  = (const float*)d_in[7];
    const float* g1  = (const float*)d_in[8];
    const float* be1 = (const float*)d_in[9];
    const float* g2  = (const float*)d_in[10];
    const float* be2 = (const float*)d_in[11];

    char* ws = (char*)d_ws;
    const size_t MB = 1ull << 20;
    unsigned short* h    = (unsigned short*)(ws + 0);         // 16 MiB
    unsigned short* q    = (unsigned short*)(ws + 16 * MB);   // 16 MiB
    unsigned short* k    = (unsigned short*)(ws + 32 * MB);   // 16 MiB
    unsigned short* vT   = (unsigned short*)(ws + 48 * MB);   // 16 MiB  [C][B*T]
    float*          xres = (float*)(ws + 64 * MB);            // 32 MiB
    float*          S    = (float*)(ws + 96 * MB);            // 64 MiB
    unsigned short* ff1  = (unsigned short*)(ws + 96 * MB);   // 64 MiB (aliases S; S dead by then)
    unsigned short* P    = (unsigned short*)(ws + 160 * MB);  // 32 MiB
    unsigned short* wqT  = (unsigned short*)(ws + 192 * MB);  // 2 MiB   [H][C]
    unsigned short* wkT  = (unsigned short*)(ws + 194 * MB);  // 2 MiB
    unsigned short* wvT  = (unsigned short*)(ws + 196 * MB);  // 2 MiB
    unsigned short* w1T  = (unsigned short*)(ws + 198 * MB);  // 8 MiB   [F][C]
    unsigned short* w2T  = (unsigned short*)(ws + 206 * MB);  // 8 MiB   [C][F]

    // transposed weight converts
    tconv_k<<<dim3(16, 16), 256, 0, stream>>>(Wq, wqT, C, C);
    tconv_k<<<dim3(16, 16), 256, 0, stream>>>(Wk, wkT, C, C);
    tconv_k<<<dim3(16, 16), 256, 0, stream>>>(Wv, wvT, C, C);
    tconv_k<<<dim3(64, 16), 256, 0, stream>>>(W1, w1T, C, F);
    tconv_k<<<dim3(16, 64), 256, 0, stream>>>(W2, w2T, F, C);

    // LN1: h = LN(x, g1, be1)
    ln_k<<<dim3(B * T), 256, 0, stream>>>(x, g1, be1, h);

    // q = h @ Wq, k = h @ Wk   (M=8192, N=1024, K=1024; B = W^T [N][K])
    dim3 gqk(C / 128, (B * T) / 128, 1);
    gemm_k<EPI_BF16, false, false><<<gqk, 256, 0, stream>>>(
        h, wqT, q, nullptr, nullptr, B * T, C, C, C, C, 1.0f, 0, 0, 0, 0);
    gemm_k<EPI_BF16, false, false><<<gqk, 256, 0, stream>>>(
        h, wkT, k, nullptr, nullptr, B * T, C, C, C, C, 1.0f, 0, 0, 0, 0);

    // vT = Wv^T @ h^T  (M=C, N=B*T, K=C; A=wvT [C][C], B=h [B*T][C])
    dim3 gvt((B * T) / 128, C / 128, 1);
    gemm_k<EPI_BF16, false, false><<<gvt, 256, 0, stream>>>(
        wvT, h, vT, nullptr, nullptr, C, B * T, C, C, C, 1.0f, 0, 0, 0, 0);

    // S = q @ k^T / 32  (per batch; causal tiles only)
    dim3 gsc(T / 128, T / 128, B);
    gemm_k<EPI_F32, true, false><<<gsc, 256, 0, stream>>>(
        q, k, S, nullptr, nullptr, T, T, C, C, C, 0.03125f,
        (long long)T * C, (long long)T * C, (long long)T * T, 0);

    // P = causal softmax(S), bf16, zero-padded to tile boundary
    softmax_k<<<dim3(T, B), 256, 0, stream>>>(S, P, T);

    // xres = x + P @ v  (B = vT [C][B*T], ldb=B*T, batch col-offset T)
    dim3 gsa(C / 128, T / 128, B);
    gemm_k<EPI_RESID_F32, false, true><<<gsa, 256, 0, stream>>>(
        P, vT, xres, nullptr, x, T, C, T, T, B * T, 1.0f,
        (long long)T * T, (long long)T, (long long)T * C, (long long)T * C);

    // LN2: h = LN(xres, g2, be2)
    ln_k<<<dim3(B * T), 256, 0, stream>>>(xres, g2, be2, h);

    // ff1 = relu(h @ W1 + b1)   (M=8192, N=4096, K=1024)
    dim3 gf1(F / 128, (B * T) / 128, 1);
    gemm_k<EPI_BIAS_RELU_BF16, false, false><<<gf1, 256, 0, stream>>>(
        h, w1T, ff1, b1, nullptr, B * T, F, C, C, C, 1.0f, 0, 0, 0, 0);

    // out = xres + ff1 @ W2 + b2   (M=8192, N=1024, K=4096)
    dim3 gf2(C / 128, (B * T) / 128, 1);
    gemm_k<EPI_BIAS_RESID_F32, false, false><<<gf2, 256, 0, stream>>>(
        ff1, w2T, (float*)d_out, b2, xres, B * T, C, F, F, F, 1.0f, 0, 0, 0, 0);
}